// Round 3
// baseline (938.509 us; speedup 1.0000x reference)
//
#include <hip/hip_runtime.h>
#include <math.h>

// Problem shape (fixed by reference setup_inputs)
#define B_DIM 64
#define CIN   512
#define COUT  512
#define A_DIM 32
#define HW    3136      // 56*56
#define BN_EPS 1e-5f

typedef float f4 __attribute__((ext_vector_type(4)));

// ---------------------------------------------------------------------------
// Fused kernel: global average pool + attention head.
//
// Pool: ONE WAVE per (b, c) row of 3136 floats (784 float4 = 12 full
// wave-passes + 16-lane tail). Nontemporal loads (x is 411 MB read-once),
// shuffle reduce, no LDS. HBM floor: 411 MB / 6.5 TB/s ~= 63 us.
//
// Att fusion: each block covers 4 rows of one batch (128 blocks per batch).
// After writing its pooled entries (agent-scope stores), each block bumps a
// per-batch counter (acq_rel, agent scope). The 128th finisher runs the
// whole attention head for that batch — no separate dispatch, and 63 of the
// 64 att executions overlap remaining pool work. No spin-waits: safe under
// any dispatch order (split-k last-block-done pattern).
// ---------------------------------------------------------------------------
__global__ __launch_bounds__(256) void fused_kernel(
    const float* __restrict__ x,
    const float* __restrict__ fc_w,        // [A, CIN]
    const float* __restrict__ bn_gamma,
    const float* __restrict__ bn_beta,
    const float* __restrict__ bn_mean,
    const float* __restrict__ bn_var,
    const float* __restrict__ ch_w,        // [CIN, A]
    const float* __restrict__ ch_b,        // [CIN]
    const float* __restrict__ f_w,         // [COUT, A]
    const float* __restrict__ f_b,         // [COUT]
    float* __restrict__ pooled,            // ws: [B*CIN]
    unsigned* __restrict__ counters,       // ws: [B], pre-zeroed
    float* __restrict__ out)               // [B*CIN] ch_att ++ [B*COUT] f_att
{
    const int t    = threadIdx.x;
    const int row  = (blockIdx.x << 2) | (t >> 6);   // global wave id = row
    const int lane = t & 63;
    const int batch = blockIdx.x >> 7;               // 128 blocks per batch

    // ---- pool phase: one wave per row ----
    {
        const f4* xr = (const f4*)(x + (size_t)row * HW);
        f4 acc = {0.f, 0.f, 0.f, 0.f};
        #pragma unroll
        for (int k = 0; k < 12; ++k) {
            f4 v = __builtin_nontemporal_load(xr + lane + (k << 6));
            acc += v;
        }
        if (lane < 16) {
            f4 v = __builtin_nontemporal_load(xr + 768 + lane);
            acc += v;
        }
        float s = (acc.x + acc.y) + (acc.z + acc.w);
        #pragma unroll
        for (int off = 32; off > 0; off >>= 1)
            s += __shfl_down(s, off, 64);
        if (lane == 0) {
            // agent-scope store: visible past this XCD's L2
            __hip_atomic_store(&pooled[row], s * (1.0f / (float)HW),
                               __ATOMIC_RELAXED, __HIP_MEMORY_SCOPE_AGENT);
        }
    }

    // ---- signal completion; last of 128 blocks runs att for this batch ----
    __shared__ unsigned last_flag;
    __syncthreads();                 // all 4 waves' stores issued & drained
    if (t == 0) {
        unsigned old = __hip_atomic_fetch_add(&counters[batch], 1u,
                                              __ATOMIC_ACQ_REL,
                                              __HIP_MEMORY_SCOPE_AGENT);
        last_flag = (old == 127u);
    }
    __syncthreads();
    if (!last_flag) return;

    // ---- att phase (one block per batch, runs exactly once) ----
    __shared__ float p[CIN];
    __shared__ float part[A_DIM][8];
    __shared__ float h[A_DIM];

    p[t]       = __hip_atomic_load(&pooled[batch * CIN + t],
                                   __ATOMIC_RELAXED, __HIP_MEMORY_SCOPE_AGENT);
    p[t + 256] = __hip_atomic_load(&pooled[batch * CIN + t + 256],
                                   __ATOMIC_RELAXED, __HIP_MEMORY_SCOPE_AGENT);
    __syncthreads();

    // h[a] partials: 8 threads per a, stride-8 over c (8 distinct banks,
    // same-address broadcast within each bank group -> conflict-free)
    const int a = t >> 3;
    const int j = t & 7;
    {
        const float* wrow = fc_w + a * CIN;
        float s = 0.f;
        #pragma unroll
        for (int k = 0; k < 64; ++k) {
            const int c = j + (k << 3);
            s += p[c] * wrow[c];
        }
        part[a][j] = s;
    }
    __syncthreads();

    if (t < A_DIM) {
        float tot = 0.f;
        #pragma unroll
        for (int jj = 0; jj < 8; ++jj) tot += part[t][jj];
        const float inv = 1.0f / sqrtf(bn_var[t] + BN_EPS);
        float hv = (tot - bn_mean[t]) * (bn_gamma[t] * inv) + bn_beta[t];
        h[t] = hv > 0.f ? hv : 0.f;
    }
    __syncthreads();

    // Each thread produces 2 channel-att and 2 filter-att outputs.
    #pragma unroll
    for (int rep = 0; rep < 2; ++rep) {
        const int c = t + rep * 256;
        float sc = ch_b[c];
        float sf = f_b[c];
        const float* cw = ch_w + c * A_DIM;
        const float* fw = f_w + c * A_DIM;
        #pragma unroll
        for (int a2 = 0; a2 < A_DIM; ++a2) {
            const float hv = h[a2];          // LDS broadcast read, free
            sc += hv * cw[a2];
            sf += hv * fw[a2];
        }
        out[batch * CIN + c]                 = 1.0f / (1.0f + expf(-sc));
        out[B_DIM * CIN + batch * COUT + c]  = 1.0f / (1.0f + expf(-sf));
    }
}

extern "C" void kernel_launch(void* const* d_in, const int* in_sizes, int n_in,
                              void* d_out, int out_size, void* d_ws, size_t ws_size,
                              hipStream_t stream) {
    const float* x        = (const float*)d_in[0];
    const float* fc_w     = (const float*)d_in[1];
    const float* bn_gamma = (const float*)d_in[2];
    const float* bn_beta  = (const float*)d_in[3];
    const float* bn_mean  = (const float*)d_in[4];
    const float* bn_var   = (const float*)d_in[5];
    const float* ch_w     = (const float*)d_in[6];
    const float* ch_b     = (const float*)d_in[7];
    const float* f_w      = (const float*)d_in[8];
    const float* f_b      = (const float*)d_in[9];
    float* out = (float*)d_out;

    float*    pooled   = (float*)d_ws;                       // 128 KB
    unsigned* counters = (unsigned*)((char*)d_ws + B_DIM * CIN * sizeof(float));

    // counters must start at 0 every call (ws is re-poisoned to 0xAA)
    hipMemsetAsync(counters, 0, B_DIM * sizeof(unsigned), stream);

    fused_kernel<<<(B_DIM * CIN) / 4, 256, 0, stream>>>(
        x, fc_w, bn_gamma, bn_beta, bn_mean, bn_var,
        ch_w, ch_b, f_w, f_b, pooled, counters, out);
}